// Round 12
// baseline (217.546 us; speedup 1.0000x reference)
//
#include <hip/hip_runtime.h>

#define NB 2048
#define NS 1024
#define NL 32

static __device__ __forceinline__ float fexp2(float x) {
#if __has_builtin(__builtin_amdgcn_exp2f)
  return __builtin_amdgcn_exp2f(x);
#else
  float r; asm("v_exp_f32 %0, %1" : "=v"(r) : "v"(x)); return r;
#endif
}
static __device__ __forceinline__ float flog2(float x) {
#if __has_builtin(__builtin_amdgcn_logf)
  return __builtin_amdgcn_logf(x);
#else
  float r; asm("v_log_f32 %0, %1" : "=v"(r) : "v"(x)); return r;
#endif
}

template<int K>
static __device__ __forceinline__ int roti(int x) {
  if constexpr (K == 0) return x;
  else return __builtin_amdgcn_update_dpp(0, x, 0x120 | K, 0xf, 0xf, true); // row_ror:K
}
template<int K>
static __device__ __forceinline__ float rotf(float x) {
  return __int_as_float(roti<K>(__float_as_int(x)));
}

// part + part[pair(lane)] via permlane swaps with s_nop hazard guards
// (validated R10: raw asm permlane needs explicit wait-states).
static __device__ __forceinline__ float plswap16_sum(float part) {
  float x, y;
  asm volatile("v_mov_b32 %0, %2\n\t"
               "v_mov_b32 %1, %2\n\t"
               "s_nop 1\n\t"
               "v_permlane16_swap_b32 %0, %1\n\t"
               "s_nop 1"
               : "=&v"(x), "=&v"(y) : "v"(part));
  return x + y;
}
static __device__ __forceinline__ float plswap32_sum(float part) {
  float x, y;
  asm volatile("v_mov_b32 %0, %2\n\t"
               "v_mov_b32 %1, %2\n\t"
               "s_nop 1\n\t"
               "v_permlane32_swap_b32 %0, %1\n\t"
               "s_nop 1"
               : "=&v"(x), "=&v"(y) : "v"(part));
  return x + y;
}
static __device__ __forceinline__ int plswap16_partner(int lane) {
  int x, y;
  asm volatile("v_mov_b32 %0, %2\n\t"
               "v_mov_b32 %1, %2\n\t"
               "s_nop 1\n\t"
               "v_permlane16_swap_b32 %0, %1\n\t"
               "s_nop 1"
               : "=&v"(x), "=&v"(y) : "v"(lane));
  return x + y - lane;
}

// 16-term rotate/FMA tree: sum_k rot_k(p) * E[k]
static __device__ __forceinline__ float tree16(float p, const float* E) {
  float a0 = p * E[0];
  float a1 = rotf<1>(p) * E[1];
  float a2 = rotf<2>(p) * E[2];
  float a3 = rotf<3>(p) * E[3];
  a0 = fmaf(rotf<4>(p),  E[4],  a0);
  a1 = fmaf(rotf<5>(p),  E[5],  a1);
  a2 = fmaf(rotf<6>(p),  E[6],  a2);
  a3 = fmaf(rotf<7>(p),  E[7],  a3);
  a0 = fmaf(rotf<8>(p),  E[8],  a0);
  a1 = fmaf(rotf<9>(p),  E[9],  a1);
  a2 = fmaf(rotf<10>(p), E[10], a2);
  a3 = fmaf(rotf<11>(p), E[11], a3);
  a0 = fmaf(rotf<12>(p), E[12], a0);
  a1 = fmaf(rotf<13>(p), E[13], a1);
  a2 = fmaf(rotf<14>(p), E[14], a2);
  a3 = fmaf(rotf<15>(p), E[15], a3);
  return (a0 + a1) + (a2 + a3);
}

__global__ void zero_out_k(float* out) {
  if (threadIdx.x < 2) out[threadIdx.x] = 0.0f;
}

// ONE wave per batch: forward (alpha) and backward (beta) chains interleaved
// in-register for 2x ILP on the latency-bound recurrence.
__global__ __launch_bounds__(64, 2)
void crf_fwd(const float* __restrict__ scores, const float* __restrict__ trans,
             const int* __restrict__ lens, const int* __restrict__ tags,
             float* __restrict__ out)
{
  constexpr float LOG2E = 1.4426950408889634f;
  constexpr float LN2   = 0.6931471805599453f;
  __shared__ float Tld[NL * NL];
  __shared__ float EmtF[2][32 * NL];
  __shared__ float EmtB[2][32 * NL];

  const int b    = blockIdx.x;
  const int lane = threadIdx.x;
  const int len  = lens[b];
  const int m    = len >> 1;            // forward: m steps -> alpha_m
  const int nB   = len - 1 - m;         // backward: nB steps -> beta_m
  const int r = lane >> 4, c = lane & 15;
  const int labA = c + ((r & 1) << 4);

  const int p16 = plswap16_partner(lane);
  const bool plOK = ((p16 & 15) == c) && ((((p16 >> 4) ^ r) & 1) == 1);
  const int pmax = (lane > p16) ? lane : p16;
  const int labB = plOK ? (c + ((pmax >= 48) ? 16 : 0))
                        : (c + (((r >> 1) & 1) << 4));

  const float* sb = scores + (size_t)b * (NS * NL);

#define STAGEF(BUFI, T0) do { \
    const float* gsrc_ = sb + (size_t)(T0) * NL; \
    _Pragma("unroll") \
    for (int k_ = 0; k_ < 4; ++k_) \
      __builtin_amdgcn_global_load_lds( \
        (const __attribute__((address_space(1))) void*)(gsrc_ + k_ * 256 + lane * 4), \
        (__attribute__((address_space(3))) void*)(&EmtF[BUFI][k_ * 256]), 16, 0, 0); \
  } while (0)
#define STAGEB(BUFI, T0) do { \
    const float* gsrc_ = sb + (size_t)(T0) * NL; \
    _Pragma("unroll") \
    for (int k_ = 0; k_ < 4; ++k_) \
      __builtin_amdgcn_global_load_lds( \
        (const __attribute__((address_space(1))) void*)(gsrc_ + k_ * 256 + lane * 4), \
        (__attribute__((address_space(3))) void*)(&EmtB[BUFI][k_ * 256]), 16, 0, 0); \
  } while (0)
#define WAITALL asm volatile("s_waitcnt vmcnt(0) lgkmcnt(0)" ::: "memory")
#define LGKM0   asm volatile("s_waitcnt lgkmcnt(0)" ::: "memory")

  // initial staging (both directions in flight together)
  int curC = 0, bufB = 0, bufF = 0;
  STAGEF(0, 0);
  if (m >= 32) STAGEF(1, 32);
  if (nB > 0) {
    curC = (len - 1) >> 5;
    STAGEB(0, curC * 32);
    if (curC >= 1 && curC * 32 - 1 >= m + 1) STAGEB(1, (curC - 1) * 32);
  }

  for (int k = lane; k < NL * NL; k += 64) Tld[k] = trans[k] * LOG2E;
  LGKM0;

  // E calibration: fwd orientation + bwd (transposed) orientation
  float EAf[16], EBf[16], EAb[16], EBb[16];
#define CFA(K) EAf[K] = fexp2(Tld[roti<K>(labA) * NL + labB]);
#define CFB(K) EBf[K] = fexp2(Tld[roti<K>(labB) * NL + labA]);
#define CBA(K) EAb[K] = fexp2(Tld[labB * NL + roti<K>(labA)]);
#define CBB(K) EBb[K] = fexp2(Tld[labA * NL + roti<K>(labB)]);
  CFA(0)  CFA(1)  CFA(2)  CFA(3)  CFA(4)  CFA(5)  CFA(6)  CFA(7)
  CFA(8)  CFA(9)  CFA(10) CFA(11) CFA(12) CFA(13) CFA(14) CFA(15)
  CFB(0)  CFB(1)  CFB(2)  CFB(3)  CFB(4)  CFB(5)  CFB(6)  CFB(7)
  CFB(8)  CFB(9)  CFB(10) CFB(11) CFB(12) CFB(13) CFB(14) CFB(15)
  CBA(0)  CBA(1)  CBA(2)  CBA(3)  CBA(4)  CBA(5)  CBA(6)  CBA(7)
  CBA(8)  CBA(9)  CBA(10) CBA(11) CBA(12) CBA(13) CBA(14) CBA(15)
  CBB(0)  CBB(1)  CBB(2)  CBB(3)  CBB(4)  CBB(5)  CBB(6)  CBB(7)
  CBB(8)  CBB(9)  CBB(10) CBB(11) CBB(12) CBB(13) CBB(14) CBB(15)
#undef CFA
#undef CFB
#undef CBA
#undef CBB

  WAITALL;  // staging chunk0s complete

  // ---- forward init ----
  float aF = Tld[31 * NL + labA];
  aF = fmaf(EmtF[0][labA], LOG2E, aF);
  float lsF = __int_as_float(__builtin_amdgcn_readfirstlane(__float_as_int(aF)));
  float uF = fexp2(aF - lsF);
  float eAf = (m >= 1) ? EmtF[0][1 * NL + labB] : 0.0f;
  float eBf = (m >= 2) ? EmtF[0][2 * NL + labA] : 0.0f;
  bool endBF = false;

  // ---- backward init ----
  float aB = Tld[labA * NL + 30];
  float lsB = __int_as_float(__builtin_amdgcn_readfirstlane(__float_as_int(aB)));
  float uB = fexp2(aB - lsB);
  float eAb = 0.0f, eBb = 0.0f;
  bool endBB = false;
  if (nB > 0) {
    eAb = EmtB[0][((len - 1) & 31) * NL + labA];
    if (nB > 1) {
      const int x = len - 2;
      if ((x >> 5) != curC) {
        WAITALL; bufB ^= 1; curC--;
        if (curC >= 1 && curC * 32 - 1 >= m + 1) STAGEB(bufB ^ 1, (curC - 1) * 32);
      }
      eBb = EmtB[bufB][(x & 31) * NL + labB];
    }
  }

#define RENF do { \
    const int eb_ = __builtin_amdgcn_readfirstlane(__float_as_int(uF)); \
    const int ex_ = (eb_ >> 23) - 127; \
    lsF += (float)ex_; \
    uF *= __int_as_float((127 - ex_) << 23); \
  } while (0)
#define RENB do { \
    const int eb_ = __builtin_amdgcn_readfirstlane(__float_as_int(uB)); \
    const int ex_ = (eb_ >> 23) - 127; \
    lsB += (float)ex_; \
    uB *= __int_as_float((127 - ex_) << 23); \
  } while (0)
#define COMB16(S) (plOK ? plswap16_sum(S) : ((S) + __shfl_xor((S), 16)))

#define PREF_F do { \
    { const int tn = t + 2; if (tn <= m) eAf = EmtF[bufF][(tn & 31) * NL + labB]; } \
    { const int tn = t + 3; \
      if (tn <= m) { \
        const int row = tn & 31; \
        if (row) { eBf = EmtF[bufF][row * NL + labA]; } \
        else { WAITALL; bufF ^= 1; eBf = EmtF[bufF][labA]; \
               if (tn + 32 <= m) STAGEF(bufF ^ 1, tn + 32); } \
      } } \
  } while (0)
#define PREF_B do { \
    { const int x = len - 3 - k; \
      if (k + 2 < nB) { \
        if ((x >> 5) != curC) { WAITALL; bufB ^= 1; curC--; \
          if (curC >= 1 && curC * 32 - 1 >= m + 1) STAGEB(bufB ^ 1, (curC - 1) * 32); } \
        eAb = EmtB[bufB][(x & 31) * NL + labA]; \
      } } \
    { const int x = len - 4 - k; \
      if (k + 3 < nB) { \
        if ((x >> 5) != curC) { WAITALL; bufB ^= 1; curC--; \
          if (curC >= 1 && curC * 32 - 1 >= m + 1) STAGEB(bufB ^ 1, (curC - 1) * 32); } \
        eBb = EmtB[bufB][(x & 31) * NL + labB]; \
      } } \
  } while (0)

  int t = 1, k = 0;
  // -------- combined main loop: both chains advance 2 steps, interleaved --------
  while (t + 1 <= m && k + 1 < nB) {
    if ((t & 3) == 1) RENF;
    if ((k & 3) == 0) RENB;
    const float wAf = fexp2(eAf * LOG2E);
    const float wBf = fexp2(eBf * LOG2E);
    const float wAb = fexp2(eAb * LOG2E);
    const float wBb = fexp2(eBb * LOG2E);
    PREF_F;
    PREF_B;
    const float sF1 = tree16(uF, EAf);         // independent chains ->
    const float sB1 = tree16(uB * wAb, EAb);   // compiler interleaves
    uF = COMB16(sF1) * wAf;
    uB = COMB16(sB1);
    const float sF2 = tree16(uF, EBf);
    const float sB2 = tree16(uB * wBb, EBb);
    uF = plswap32_sum(sF2) * wBf;
    uB = plswap32_sum(sB2);
    t += 2; k += 2;
  }
  // -------- forward remainder --------
  while (t + 1 <= m) {
    if ((t & 3) == 1) RENF;
    const float wAf = fexp2(eAf * LOG2E);
    const float wBf = fexp2(eBf * LOG2E);
    PREF_F;
    uF = COMB16(tree16(uF, EAf)) * wAf;
    uF = plswap32_sum(tree16(uF, EBf)) * wBf;
    t += 2;
  }
  if (t <= m) {
    if ((t & 3) == 1) RENF;
    const float wAf = fexp2(eAf * LOG2E);
    uF = COMB16(tree16(uF, EAf)) * wAf;
    endBF = true;
  }
  // -------- backward remainder --------
  while (k + 1 < nB) {
    if ((k & 3) == 0) RENB;
    const float wAb = fexp2(eAb * LOG2E);
    const float wBb = fexp2(eBb * LOG2E);
    PREF_B;
    uB = COMB16(tree16(uB * wAb, EAb));
    uB = plswap32_sum(tree16(uB * wBb, EBb));
    k += 2;
  }
  if (k < nB) {
    if ((k & 3) == 0) RENB;
    const float wAb = fexp2(eAb * LOG2E);
    uB = COMB16(tree16(uB * wAb, EAb));
    endBB = true;
  }

  // -------- junction: Z = ln2 * LSE2_j(alphalog[j] + betalog[j]) --------
  float* slot = &EmtF[0][0];   // Emt dead; single wave, order via lgkmcnt
  LGKM0;
  slot[(endBF ? labB : labA)]      = lsF + flog2(uF);
  slot[32 + (endBB ? labB : labA)] = lsB + flog2(uB);
  LGKM0;
  float v2 = (lane < 32) ? (slot[lane] + slot[32 + lane]) : -3.0e38f;
  float mm = v2;
  #pragma unroll
  for (int w = 32; w; w >>= 1) mm = fmaxf(mm, __shfl_xor(mm, w));
  float ssum = fexp2(v2 - mm);
  #pragma unroll
  for (int w = 32; w; w >>= 1) ssum += __shfl_xor(ssum, w);
  if (lane == 0) atomicAdd(out + 0, LN2 * (mm + flog2(ssum)));

  // -------- labeled score --------
  const int* tb = tags + (size_t)b * NS;
  float lab = 0.0f;
  if (lane == 0) {
    const int tg0 = tb[0];
    lab += Tld[31 * NL + tg0] + LOG2E * sb[tg0];
    const int tgl = tb[len - 1];
    lab += Tld[tgl * NL + 30];
  }
  for (int t2 = 1 + lane; t2 < len; t2 += 64) {
    const int tp = tb[t2 - 1];
    const int tg = tb[t2];
    lab += Tld[tp * NL + tg] + LOG2E * sb[(size_t)t2 * NL + tg];
  }
  #pragma unroll
  for (int w = 32; w; w >>= 1) lab += __shfl_xor(lab, w);
  if (lane == 0) atomicAdd(out + 1, LN2 * lab);
#undef STAGEF
#undef STAGEB
#undef WAITALL
#undef LGKM0
#undef RENF
#undef RENB
#undef COMB16
#undef PREF_F
#undef PREF_B
}

extern "C" void kernel_launch(void* const* d_in, const int* in_sizes, int n_in,
                              void* d_out, int out_size, void* d_ws, size_t ws_size,
                              hipStream_t stream) {
  const float* scores = (const float*)d_in[0];
  const float* trans  = (const float*)d_in[1];
  const int*   lens   = (const int*)d_in[2];
  const int*   tags   = (const int*)d_in[3];
  float* out = (float*)d_out;

  zero_out_k<<<1, 64, 0, stream>>>(out);
  crf_fwd<<<NB, 64, 0, stream>>>(scores, trans, lens, tags, out);
}

// Round 13
// 149.027 us; speedup vs baseline: 1.4598x; 1.4598x over previous
//
#include <hip/hip_runtime.h>

#define NB 2048
#define NS 1024
#define NL 32

static __device__ __forceinline__ float fexp2(float x) {
#if __has_builtin(__builtin_amdgcn_exp2f)
  return __builtin_amdgcn_exp2f(x);
#else
  float r; asm("v_exp_f32 %0, %1" : "=v"(r) : "v"(x)); return r;
#endif
}
static __device__ __forceinline__ float flog2(float x) {
#if __has_builtin(__builtin_amdgcn_logf)
  return __builtin_amdgcn_logf(x);
#else
  float r; asm("v_log_f32 %0, %1" : "=v"(r) : "v"(x)); return r;
#endif
}

template<int K>
static __device__ __forceinline__ int roti(int x) {
  if constexpr (K == 0) return x;
  else return __builtin_amdgcn_update_dpp(0, x, 0x120 | K, 0xf, 0xf, true); // row_ror:K
}
template<int K>
static __device__ __forceinline__ float rotf(float x) {
  return __int_as_float(roti<K>(__float_as_int(x)));
}

// part + part[pair(lane)] via permlane swaps with s_nop hazard guards (R10-validated).
static __device__ __forceinline__ float plswap16_sum(float part) {
  float x, y;
  asm volatile("v_mov_b32 %0, %2\n\t"
               "v_mov_b32 %1, %2\n\t"
               "s_nop 1\n\t"
               "v_permlane16_swap_b32 %0, %1\n\t"
               "s_nop 1"
               : "=&v"(x), "=&v"(y) : "v"(part));
  return x + y;
}
static __device__ __forceinline__ float plswap32_sum(float part) {
  float x, y;
  asm volatile("v_mov_b32 %0, %2\n\t"
               "v_mov_b32 %1, %2\n\t"
               "s_nop 1\n\t"
               "v_permlane32_swap_b32 %0, %1\n\t"
               "s_nop 1"
               : "=&v"(x), "=&v"(y) : "v"(part));
  return x + y;
}
static __device__ __forceinline__ int plswap16_partner(int lane) {
  int x, y;
  asm volatile("v_mov_b32 %0, %2\n\t"
               "v_mov_b32 %1, %2\n\t"
               "s_nop 1\n\t"
               "v_permlane16_swap_b32 %0, %1\n\t"
               "s_nop 1"
               : "=&v"(x), "=&v"(y) : "v"(lane));
  return x + y - lane;
}

// 16-term rotate/FMA tree: sum_k rot_k(p) * E[k]
static __device__ __forceinline__ float tree16(float p, const float* E) {
  float a0 = p * E[0];
  float a1 = rotf<1>(p) * E[1];
  float a2 = rotf<2>(p) * E[2];
  float a3 = rotf<3>(p) * E[3];
  a0 = fmaf(rotf<4>(p),  E[4],  a0);
  a1 = fmaf(rotf<5>(p),  E[5],  a1);
  a2 = fmaf(rotf<6>(p),  E[6],  a2);
  a3 = fmaf(rotf<7>(p),  E[7],  a3);
  a0 = fmaf(rotf<8>(p),  E[8],  a0);
  a1 = fmaf(rotf<9>(p),  E[9],  a1);
  a2 = fmaf(rotf<10>(p), E[10], a2);
  a3 = fmaf(rotf<11>(p), E[11], a3);
  a0 = fmaf(rotf<12>(p), E[12], a0);
  a1 = fmaf(rotf<13>(p), E[13], a1);
  a2 = fmaf(rotf<14>(p), E[14], a2);
  a3 = fmaf(rotf<15>(p), E[15], a3);
  return (a0 + a1) + (a2 + a3);
}

__global__ void zero_out_k(float* out) {
  if (threadIdx.x < 2) out[threadIdx.x] = 0.0f;
}

// 2 waves/block: wave0 = forward alpha chain, wave1 = backward beta chain.
// Emits gathered DIRECTLY from global (one 128B line/step) into an 8-deep
// register pipeline — no LDS on the recurrence path except the combine swaps.
__global__ __launch_bounds__(128, 2)
void crf_fwd(const float* __restrict__ scores, const float* __restrict__ trans,
             const int* __restrict__ lens, const int* __restrict__ tags,
             float* __restrict__ out)
{
  constexpr float LOG2E = 1.4426950408889634f;
  constexpr float LN2   = 0.6931471805599453f;
  __shared__ float Tld[NL * NL];
  __shared__ float slotm[64];

  const int b    = blockIdx.x;
  const int tid  = threadIdx.x;
  const int wid  = tid >> 6;
  const int lane = tid & 63;
  const int len  = lens[b];
  const int m    = len >> 1;            // forward: m steps -> alpha_m
  const int nB   = len - 1 - m;         // backward: nB steps -> beta_m
  const int r = lane >> 4, c = lane & 15;
  const int labA = c + ((r & 1) << 4);

  const int p16 = plswap16_partner(lane);
  const bool plOK = ((p16 & 15) == c) && ((((p16 >> 4) ^ r) & 1) == 1);
  const int pmax = (lane > p16) ? lane : p16;
  const int labB = plOK ? (c + ((pmax >= 48) ? 16 : 0))
                        : (c + (((r >> 1) & 1) << 4));

  const float* sbf = scores + (size_t)b * (NS * NL);

  for (int k2 = tid; k2 < NL * NL; k2 += 128) Tld[k2] = trans[k2] * LOG2E;
  __syncthreads();

#define COMB16(S) (plOK ? plswap16_sum(S) : ((S) + __shfl_xor((S), 16)))
// clamped global emit gather: row in [0, len-1]; one 128B line per load
#define LDROW(DST, ROW, LAB) do { \
    int r_ = (ROW); r_ = r_ < 0 ? 0 : r_; r_ = r_ > len - 1 ? len - 1 : r_; \
    DST = sbf[(size_t)r_ * NL + (LAB)]; \
  } while (0)

  float u, ls;
  bool endB = false;

  if (wid == 0) {
    // ---------------- forward ----------------
    float EA[16], EB[16];
#define CFA(K) EA[K] = fexp2(Tld[roti<K>(labA) * NL + labB]);
#define CFB(K) EB[K] = fexp2(Tld[roti<K>(labB) * NL + labA]);
    CFA(0)  CFA(1)  CFA(2)  CFA(3)  CFA(4)  CFA(5)  CFA(6)  CFA(7)
    CFA(8)  CFA(9)  CFA(10) CFA(11) CFA(12) CFA(13) CFA(14) CFA(15)
    CFB(0)  CFB(1)  CFB(2)  CFB(3)  CFB(4)  CFB(5)  CFB(6)  CFB(7)
    CFB(8)  CFB(9)  CFB(10) CFB(11) CFB(12) CFB(13) CFB(14) CFB(15)
#undef CFA
#undef CFB
    float a0 = Tld[31 * NL + labA] + LOG2E * sbf[labA];
    ls = __int_as_float(__builtin_amdgcn_readfirstlane(__float_as_int(a0)));
    u = fexp2(a0 - ls);

#define RENORM do { \
    const int eb_ = __builtin_amdgcn_readfirstlane(__float_as_int(u)); \
    const int ex_ = (eb_ >> 23) - 127; \
    ls += (float)ex_; \
    u *= __int_as_float((127 - ex_) << 23); \
  } while (0)

    // 8-deep emit pipeline: P = steps t..t+3, Q = t+4..t+7
    float P0, P1, P2, P3, Q0, Q1, Q2, Q3;
    int t = 1;
    LDROW(P0, 1, labB); LDROW(P1, 2, labA); LDROW(P2, 3, labB); LDROW(P3, 4, labA);
    LDROW(Q0, 5, labB); LDROW(Q1, 6, labA); LDROW(Q2, 7, labB); LDROW(Q3, 8, labA);

#define FBODY(B0, B1, B2, B3) do { \
    RENORM; \
    const float w0 = fexp2(B0 * LOG2E); \
    const float w1 = fexp2(B1 * LOG2E); \
    const float w2 = fexp2(B2 * LOG2E); \
    const float w3 = fexp2(B3 * LOG2E); \
    LDROW(B0, t + 8,  labB); LDROW(B1, t + 9,  labA); \
    LDROW(B2, t + 10, labB); LDROW(B3, t + 11, labA); \
    u = COMB16(tree16(u, EA)) * w0; \
    u = plswap32_sum(tree16(u, EB)) * w1; \
    u = COMB16(tree16(u, EA)) * w2; \
    u = plswap32_sum(tree16(u, EB)) * w3; \
  } while (0)

    while (t + 7 <= m) {
      FBODY(P0, P1, P2, P3); t += 4;
      FBODY(Q0, Q1, Q2, Q3); t += 4;
    }
    if (t + 3 <= m) { FBODY(P0, P1, P2, P3); t += 4; }
    // drain (<=3 steps), direct loads
    while (t <= m) {
      if ((t & 3) == 1) RENORM;
      if (t & 1) {          // A-step
        float e; LDROW(e, t, labB);
        u = COMB16(tree16(u, EA)) * fexp2(e * LOG2E);
        endB = true;
      } else {              // B-step
        float e; LDROW(e, t, labA);
        u = plswap32_sum(tree16(u, EB)) * fexp2(e * LOG2E);
        endB = false;
      }
      t++;
    }
#undef FBODY
  } else {
    // ---------------- backward ----------------
    float EA[16], EB[16];
#define CBA(K) EA[K] = fexp2(Tld[labB * NL + roti<K>(labA)]);
#define CBB(K) EB[K] = fexp2(Tld[labA * NL + roti<K>(labB)]);
    CBA(0)  CBA(1)  CBA(2)  CBA(3)  CBA(4)  CBA(5)  CBA(6)  CBA(7)
    CBA(8)  CBA(9)  CBA(10) CBA(11) CBA(12) CBA(13) CBA(14) CBA(15)
    CBB(0)  CBB(1)  CBB(2)  CBB(3)  CBB(4)  CBB(5)  CBB(6)  CBB(7)
    CBB(8)  CBB(9)  CBB(10) CBB(11) CBB(12) CBB(13) CBB(14) CBB(15)
#undef CBA
#undef CBB
    float a0 = Tld[labA * NL + 30];
    ls = __int_as_float(__builtin_amdgcn_readfirstlane(__float_as_int(a0)));
    u = fexp2(a0 - ls);

    float P0, P1, P2, P3, Q0, Q1, Q2, Q3;
    int k = 0;
    LDROW(P0, len - 1, labA); LDROW(P1, len - 2, labB);
    LDROW(P2, len - 3, labA); LDROW(P3, len - 4, labB);
    LDROW(Q0, len - 5, labA); LDROW(Q1, len - 6, labB);
    LDROW(Q2, len - 7, labA); LDROW(Q3, len - 8, labB);

#define BBODY(B0, B1, B2, B3) do { \
    RENORM; \
    const float w0 = fexp2(B0 * LOG2E); \
    const float w1 = fexp2(B1 * LOG2E); \
    const float w2 = fexp2(B2 * LOG2E); \
    const float w3 = fexp2(B3 * LOG2E); \
    LDROW(B0, len - 1 - k - 8,  labA); LDROW(B1, len - 2 - k - 8,  labB); \
    LDROW(B2, len - 3 - k - 8,  labA); LDROW(B3, len - 4 - k - 8,  labB); \
    u = COMB16(tree16(u * w0, EA)); \
    u = plswap32_sum(tree16(u * w1, EB)); \
    u = COMB16(tree16(u * w2, EA)); \
    u = plswap32_sum(tree16(u * w3, EB)); \
  } while (0)

    while (k + 7 < nB) {
      BBODY(P0, P1, P2, P3); k += 4;
      BBODY(Q0, Q1, Q2, Q3); k += 4;
    }
    if (k + 3 < nB) { BBODY(P0, P1, P2, P3); k += 4; }
    while (k < nB) {
      if ((k & 3) == 0) RENORM;
      if (!(k & 1)) {       // A-step
        float e; LDROW(e, len - 1 - k, labA);
        u = COMB16(tree16(u * fexp2(e * LOG2E), EA));
        endB = true;
      } else {              // B-step
        float e; LDROW(e, len - 1 - k, labB);
        u = plswap32_sum(tree16(u * fexp2(e * LOG2E), EB));
        endB = false;
      }
      k++;
    }
#undef BBODY
  }

  // -------- junction: Z = ln2 * LSE2_j(alphalog[j] + betalog[j]) --------
  slotm[wid * 32 + (endB ? labB : labA)] = ls + flog2(u);
  __syncthreads();

  if (wid == 0) {
    float v2 = (lane < 32) ? (slotm[lane] + slotm[32 + lane]) : -3.0e38f;
    float mm = v2;
    #pragma unroll
    for (int w = 32; w; w >>= 1) mm = fmaxf(mm, __shfl_xor(mm, w));
    float ssum = fexp2(v2 - mm);
    #pragma unroll
    for (int w = 32; w; w >>= 1) ssum += __shfl_xor(ssum, w);
    if (lane == 0) atomicAdd(out + 0, LN2 * (mm + flog2(ssum)));

    // -------- labeled score --------
    const int* tb = tags + (size_t)b * NS;
    float lab = 0.0f;
    if (lane == 0) {
      const int tg0 = tb[0];
      lab += Tld[31 * NL + tg0] + LOG2E * sbf[tg0];
      const int tgl = tb[len - 1];
      lab += Tld[tgl * NL + 30];
    }
    for (int t2 = 1 + lane; t2 < len; t2 += 64) {
      const int tp = tb[t2 - 1];
      const int tg = tb[t2];
      lab += Tld[tp * NL + tg] + LOG2E * sbf[(size_t)t2 * NL + tg];
    }
    #pragma unroll
    for (int w = 32; w; w >>= 1) lab += __shfl_xor(lab, w);
    if (lane == 0) atomicAdd(out + 1, LN2 * lab);
  }
#undef COMB16
#undef LDROW
#undef RENORM
}

extern "C" void kernel_launch(void* const* d_in, const int* in_sizes, int n_in,
                              void* d_out, int out_size, void* d_ws, size_t ws_size,
                              hipStream_t stream) {
  const float* scores = (const float*)d_in[0];
  const float* trans  = (const float*)d_in[1];
  const int*   lens   = (const int*)d_in[2];
  const int*   tags   = (const int*)d_in[3];
  float* out = (float*)d_out;

  zero_out_k<<<1, 64, 0, stream>>>(out);
  crf_fwd<<<NB, 128, 0, stream>>>(scores, trans, lens, tags, out);
}